// Round 8
// baseline (406.086 us; speedup 1.0000x reference)
//
#include <hip/hip_runtime.h>

// CrossAttentionSpatial: GN(x), GN(condA), Q/K/V 1x1 convs, 4096x4096 attention.
// B=8, C=256, E=512, N=M=4096, GROUPS=32.
//
// R8 = R7 with host-side typo fixed (launch arg `wv` -> `vw`).
// R7: attention K-loop restructured. (1) P stays in REGISTERS: S^T C-layout ->
// PV A-layout differs only in the h-half split of m; fixed with 2 shfl_xor(32)
// per m-16-chunk (4/iter). Each wave owns its m-half and accumulates all 256
// channels (acc 128 VGPR); mh-halves summed once via LDS at epilogue.
// (2) K staged via __builtin_amdgcn_global_load_lds (16B) into a 2x32KB
// double buffer: zero staging VGPRs, async DMA, ONE barrier/iter (its vmcnt
// drain completes the DMA). (3) projQ+projKV merged into one launch.

typedef _Float16 half8 __attribute__((ext_vector_type(8)));
typedef _Float16 half4v __attribute__((ext_vector_type(4)));
typedef _Float16 half16 __attribute__((ext_vector_type(16)));
typedef float f32x4 __attribute__((ext_vector_type(4)));
typedef float f32x16 __attribute__((ext_vector_type(16)));
typedef unsigned u32x8 __attribute__((ext_vector_type(8)));
typedef unsigned u32x4 __attribute__((ext_vector_type(4)));

#define MFMA16(a, b, c) __builtin_amdgcn_mfma_f32_16x16x32_f16((a), (b), (c), 0, 0, 0)
#define MFMA32(a, b, c) __builtin_amdgcn_mfma_f32_32x32x16_f16((a), (b), (c), 0, 0, 0)

__device__ __forceinline__ void gload_lds16(const void* g, void* l) {
  __builtin_amdgcn_global_load_lds(
      (const __attribute__((address_space(1))) unsigned int*)g,
      (__attribute__((address_space(3))) unsigned int*)l, 16, 0, 0);
}

// ---------------------------------------------------------------------------
// Kernel 1: group stats (blocks 0..511) + weight fp32->fp16 frag-tiling
// (blocks 512..671). Unchanged from R6.
// ---------------------------------------------------------------------------
__global__ __launch_bounds__(256) void statswconv_kernel(
    const float* __restrict__ x, const float* __restrict__ condA,
    float* __restrict__ sx, float* __restrict__ sc,
    const float* __restrict__ wq, const float* __restrict__ wk,
    const float* __restrict__ wv, _Float16* __restrict__ wqt,
    _Float16* __restrict__ wkt, _Float16* __restrict__ wvt) {
  int bid = blockIdx.x;
  int t = threadIdx.x;
  if (bid >= 512) {
    int i = (bid - 512) * 256 + t;
    const float* src;
    _Float16* dst;
    int cin, ksbits, gi;
    if (i < 8192) { src = wq; dst = wqt; cin = 256; ksbits = 3; gi = i; }
    else if (i < 24576) { src = wk; dst = wkt; cin = 512; ksbits = 4; gi = i - 8192; }
    else { src = wv; dst = wvt; cin = 512; ksbits = 4; gi = i - 24576; }
    int tile = gi >> 6, g = gi & 63;
    int otile = tile >> ksbits, ks = tile & ((1 << ksbits) - 1);
    int o = otile * 16 + (g & 15), k = ks * 32 + (g >> 4) * 8;
    const float* s = src + (size_t)o * cin + k;
    half8 hv;
#pragma unroll
    for (int j = 0; j < 8; j++) hv[j] = (_Float16)s[j];
    *(half8*)(dst + (size_t)gi * 8) = hv;
    return;
  }
  const float4* src;
  int nf4;
  float* dst;
  float inv_n;
  if (bid < 256) {
    src = (const float4*)(x + (size_t)bid * 32768);
    nf4 = 8192;
    dst = sx + bid * 2;
    inv_n = 1.0f / 32768.0f;
  } else {
    int j = bid - 256;
    src = (const float4*)(condA + (size_t)j * 65536);
    nf4 = 16384;
    dst = sc + j * 2;
    inv_n = 1.0f / 65536.0f;
  }
  float s = 0.f, s2 = 0.f;
  for (int i = t; i < nf4; i += 256) {
    float4 v = src[i];
    s += v.x + v.y + v.z + v.w;
    s2 += v.x * v.x + v.y * v.y + v.z * v.z + v.w * v.w;
  }
#pragma unroll
  for (int m = 1; m <= 32; m <<= 1) {
    s += __shfl_xor(s, m, 64);
    s2 += __shfl_xor(s2, m, 64);
  }
  __shared__ float red[8];
  int w = t >> 6;
  if ((t & 63) == 0) { red[w * 2] = s; red[w * 2 + 1] = s2; }
  __syncthreads();
  if (t == 0) {
    float S = red[0] + red[2] + red[4] + red[6];
    float S2 = red[1] + red[3] + red[5] + red[7];
    float mu = S * inv_n;
    float var = S2 * inv_n - mu * mu;
    dst[0] = mu;
    dst[1] = rsqrtf(var + 1e-5f);
  }
}

// ---------------------------------------------------------------------------
// Kernel 2: normalize + transpose -> frag-tiled fp16 (unchanged from R6).
// ---------------------------------------------------------------------------
__global__ __launch_bounds__(256) void ntrans_kernel(
    const float* __restrict__ x, const float* __restrict__ condA,
    const float* __restrict__ statsx, const float* __restrict__ statsc,
    const float* __restrict__ gxw, const float* __restrict__ gxb,
    const float* __restrict__ gcw, const float* __restrict__ gcb,
    _Float16* __restrict__ hxTt, _Float16* __restrict__ h1Tt) {
  int bid = blockIdx.x;
  const float *src, *stats, *gw, *gb;
  _Float16* dst;
  int CH, gsh, bid2;
  if (bid < 2048) {
    src = x; stats = statsx; gw = gxw; gb = gxb; dst = hxTt;
    CH = 256; gsh = 3; bid2 = bid;
  } else {
    src = condA; stats = statsc; gw = gcw; gb = gcb; dst = h1Tt;
    CH = 512; gsh = 4; bid2 = bid - 2048;
  }
  int b = bid2 & 7, nt = (bid2 >> 3) & 63, ctile = bid2 >> 9;
  int n0 = nt * 64, c0 = ctile * 64;
  int t = threadIdx.x;
  __shared__ float tile[64][65];

  int cl = t >> 2;
  int c = c0 + cl;
  const float* st = stats + ((size_t)b * 32 + (c >> gsh)) * 2;
  float mu = st[0], rs = st[1];
  float a = rs * gw[c];
  float bb = gb[c] - mu * a;
  const float* srow = src + ((size_t)(b * CH + c)) * 4096 + n0 + (t & 3) * 16;
#pragma unroll
  for (int i = 0; i < 4; i++) {
    float4 v = *(const float4*)(srow + 4 * i);
    int nn = (t & 3) * 16 + 4 * i;
    tile[cl][nn + 0] = v.x * a + bb;
    tile[cl][nn + 1] = v.y * a + bb;
    tile[cl][nn + 2] = v.z * a + bb;
    tile[cl][nn + 3] = v.w * a + bb;
  }
  __syncthreads();
  int nl = t >> 2;
  half8 ov[2];
#pragma unroll
  for (int u = 0; u < 2; u++)
#pragma unroll
    for (int i = 0; i < 8; i++) ov[u][i] = (_Float16)tile[(t & 3) * 16 + 8 * u + i][nl];
  int n = n0 + nl;
  size_t tb = ((size_t)b * 256 + (n >> 4)) * (CH >> 5);
  int ca = c0 + (t & 3) * 16;
#pragma unroll
  for (int u = 0; u < 2; u++) {
    int cc = ca + 8 * u;
    size_t addr = ((tb + (cc >> 5)) * 64 + (n & 15) + 16 * ((cc >> 3) & 3)) * 8;
    *(half8*)(dst + addr) = ov[u];
  }
}

// ---------------------------------------------------------------------------
// Kernel 3: merged projections. Blocks 0..511: Q (R6 projQ body).
// Blocks 512..1023: fused K+V (R6 projKV body). One 64KB LDS stage buffer.
// ---------------------------------------------------------------------------
__global__ __launch_bounds__(256, 2) void projQKV_kernel(
    const _Float16* __restrict__ HxT, const _Float16* __restrict__ H1T,
    const _Float16* __restrict__ Wq, const _Float16* __restrict__ Wk,
    const _Float16* __restrict__ Wv, const float* __restrict__ qb,
    const float* __restrict__ kb, const float* __restrict__ vb,
    _Float16* __restrict__ Qt, _Float16* __restrict__ Kt,
    _Float16* __restrict__ Vt) {
  __shared__ __align__(16) _Float16 hbuf[32768];  // 64KB
  half8* hb = (half8*)hbuf;
  int t = threadIdx.x, l = t & 63, w = t >> 6;
  int c15 = l & 15, q = l >> 4;

  if (blockIdx.x < 512) {
    // ---- Q path ----
    int bid = blockIdx.x;
    int b = bid & 7, nt = bid >> 3;
    {
      const half8* sg = (const half8*)HxT + (size_t)(b * 256 + nt * 4) * 512;
#pragma unroll
      for (int i = 0; i < 8; i++) hb[t + 256 * i] = sg[t + 256 * i];
    }
    __syncthreads();
    const half8* wt8 = (const half8*)Wq;
#pragma unroll
    for (int p = 0; p < 2; p++) {
      int oa = (p * 4 + w) * 2;
      f32x4 acc[2][4] = {};
#pragma unroll
      for (int ks = 0; ks < 8; ks++) {
        half8 af0 = wt8[((size_t)(oa + 0) * 8 + ks) * 64 + l];
        half8 af1 = wt8[((size_t)(oa + 1) * 8 + ks) * 64 + l];
#pragma unroll
        for (int nt2 = 0; nt2 < 4; nt2++) {
          half8 bf = hb[(nt2 * 8 + ks) * 64 + l];
          acc[0][nt2] = MFMA16(af0, bf, acc[0][nt2]);
          acc[1][nt2] = MFMA16(af1, bf, acc[1][nt2]);
        }
      }
#pragma unroll
      for (int j = 0; j < 2; j++) {
        int o4 = (oa + j) * 16 + 4 * q;
        f32x4 bv = *(const f32x4*)(qb + o4);
#pragma unroll
        for (int nt2 = 0; nt2 < 4; nt2++) {
          half4v hv;
#pragma unroll
          for (int r = 0; r < 4; r++) hv[r] = (_Float16)((acc[j][nt2][r] + bv[r]) * 0.0625f);
          size_t addr = ((((size_t)b * 128 + nt * 2 + (nt2 >> 1)) * 16 + (oa + j)) * 64 +
                         (nt2 & 1) * 16 + c15 + 32 * (q >> 1)) * 8 + (q & 1) * 4;
          *(half4v*)(Qt + addr) = hv;
        }
      }
    }
    return;
  }
  // ---- fused K+V path ----
  int bid = blockIdx.x - 512;
  int b = bid & 7, mt = bid >> 3;
  int m0 = mt * 64;
  {
    const half8* sg = (const half8*)H1T + (size_t)(b * 256 + mt * 4) * 1024;
#pragma unroll
    for (int i = 0; i < 16; i++) hb[t + 256 * i] = sg[t + 256 * i];
  }
  __syncthreads();
  const half8* wk8 = (const half8*)Wk;
  const half8* wv8 = (const half8*)Wv;
#pragma unroll
  for (int p = 0; p < 2; p++) {
    int oa = (p * 4 + w) * 2;
    f32x4 acck[2][4] = {};
    f32x4 accv[4][2] = {};
#pragma unroll
    for (int ks = 0; ks < 16; ks++) {
      half8 kf0 = wk8[((size_t)(oa + 0) * 16 + ks) * 64 + l];
      half8 kf1 = wk8[((size_t)(oa + 1) * 16 + ks) * 64 + l];
      half8 vf0 = wv8[((size_t)(oa + 0) * 16 + ks) * 64 + l];
      half8 vf1 = wv8[((size_t)(oa + 1) * 16 + ks) * 64 + l];
#pragma unroll
      for (int nt2 = 0; nt2 < 4; nt2++) {
        half8 lf = hb[(nt2 * 16 + ks) * 64 + l];
        acck[0][nt2] = MFMA16(kf0, lf, acck[0][nt2]);
        acck[1][nt2] = MFMA16(kf1, lf, acck[1][nt2]);
        accv[nt2][0] = MFMA16(lf, vf0, accv[nt2][0]);
        accv[nt2][1] = MFMA16(lf, vf1, accv[nt2][1]);
      }
    }
#pragma unroll
    for (int j = 0; j < 2; j++) {
      int o4 = (oa + j) * 16 + 4 * q;
      f32x4 bv = *(const f32x4*)(kb + o4);
#pragma unroll
      for (int nt2 = 0; nt2 < 4; nt2++) {
        half4v hv;
#pragma unroll
        for (int r = 0; r < 4; r++) hv[r] = (_Float16)(acck[j][nt2][r] + bv[r]);
        size_t addr = ((((size_t)b * 128 + mt * 2 + (nt2 >> 1)) * 16 + (oa + j)) * 64 +
                       (nt2 & 1) * 16 + c15 + 32 * (q >> 1)) * 8 + (q & 1) * 4;
        *(half4v*)(Kt + addr) = hv;
      }
    }
#pragma unroll
    for (int nt2 = 0; nt2 < 4; nt2++) {
      int m = m0 + nt2 * 16 + 4 * q;
      size_t mbase = ((size_t)b * 256 + (m >> 4)) * 8;
#pragma unroll
      for (int j = 0; j < 2; j++) {
        int c = (oa + j) * 16 + c15;
        float bs = vb[c];
        half4v hv;
#pragma unroll
        for (int r = 0; r < 4; r++) hv[r] = (_Float16)(accv[nt2][j][r] + bs);
        size_t addr = ((mbase + (c >> 5)) * 64 + (c & 31) + ((q >> 1) << 5)) * 8 + (q & 1) * 4;
        *(half4v*)(Vt + addr) = hv;
      }
    }
  }
}

// ---------------------------------------------------------------------------
// Kernel 4 (R7): single-barrier flash attention, P in registers.
// Waves: (mh = w&1) m-half x (nh = w>>1) n-half. Per iter: async-DMA K(i+1)
// into alt buffer | load V(u=0) | S^T (16 MFMA from kbuf[cur]) | exp + pack |
// h-swap shuffles -> P A-frags | PV u=0 (8 MFMA, all 256 c) | load V(u=1) |
// PV u=1 | __syncthreads (drains DMA + releases cur). Epilogue: mh=1 waves
// dump acc (32KB/wave) into kbuf, mh=0 adds, normalizes by l, stores.
// ---------------------------------------------------------------------------
__global__ __launch_bounds__(256, 2) void attn_kernel(
    const _Float16* __restrict__ Qt, const _Float16* __restrict__ Kt,
    const _Float16* __restrict__ Vt, float* __restrict__ out) {
  int bid = blockIdx.x;
  int b = bid & 7, nt = bid >> 3;
  int n0 = nt * 64;
  int t = threadIdx.x, l = t & 63, w = t >> 6;
  int l31 = l & 31, h = l >> 5;
  int mh = w & 1, nh = w >> 1;

  __shared__ __align__(16) _Float16 kbuf[2][16384];  // 2 x 32KB K dbuf
  __shared__ float lsw[2][64];

  // Q B-frags: contiguous 1KB wave loads from tiled Qt
  half8 qf[16];
  {
    const half8* qt8 = (const half8*)Qt + ((size_t)(b * 128 + nt * 2 + nh) * 16) * 64 + l;
#pragma unroll
    for (int ks = 0; ks < 16; ks++) qf[ks] = qt8[ks * 64];
  }

  const half8* ktb = (const half8*)Kt + (size_t)b * 131072;
  const half8* vt8 = (const half8*)Vt + (size_t)b * 131072;

  f32x16 acc[8] = {};
  float l_part = 0.f;

  // stage K tile 0 (async DMA; the pre-loop barrier drains it)
  {
    const half8* g = ktb + t;
    _Float16* d = kbuf[0] + t * 8;
#pragma unroll
    for (int i = 0; i < 8; i++) gload_lds16(g + i * 256, d + i * 2048);
  }
  __syncthreads();

  for (int it = 0; it < 64; it++) {
    const half8* cur = (const half8*)kbuf[it & 1];
    if (it < 63) {  // async-DMA next K tile into the alt buffer
      const half8* g = ktb + (it + 1) * 2048 + t;
      _Float16* d = kbuf[(it + 1) & 1] + t * 8;
#pragma unroll
      for (int i = 0; i < 8; i++) gload_lds16(g + i * 256, d + i * 2048);
    }
    // V frags u=0 (this wave's m-16-chunk mh*2+0, all 8 c-tiles)
    half8 vf[8];
#pragma unroll
    for (int ct = 0; ct < 8; ct++)
      vf[ct] = vt8[((size_t)(it * 4 + mh * 2) * 8 + ct) * 64 + l];

    // ---- S^T = K Q^T : conflict-free lane-contiguous frag reads ----
    f32x16 s = {};
#pragma unroll
    for (int ks = 0; ks < 16; ks++) {
      half8 kf = cur[(mh * 16 + ks) * 64 + l];
      s = MFMA32(kf, qf[ks], s);
    }

    // ---- exp + pack to f16 (C-reg order) ----
    half16 ph;
#pragma unroll
    for (int r = 0; r < 16; r++) {
      float e = __expf(s[r]);
      l_part += e;
      ph[r] = (_Float16)e;
    }
    u32x8 pu = __builtin_bit_cast(u32x8, ph);

    // ---- C-layout -> A-layout: swap m-quads across h-halves (lane^32) ----
    // chunk c2 covers m_local 16*c2..16*c2+15; A-frag j-order = 8h + j.
    half8 pf[2];
#pragma unroll
    for (int c2 = 0; c2 < 2; c2++) {
      unsigned s0 = h ? pu[c2 * 4 + 0] : pu[c2 * 4 + 2];
      unsigned s1 = h ? pu[c2 * 4 + 1] : pu[c2 * 4 + 3];
      unsigned r0 = __shfl_xor(s0, 32, 64);
      unsigned r1 = __shfl_xor(s1, 32, 64);
      u32x4 fr;
      fr[0] = h ? r0 : pu[c2 * 4 + 0];
      fr[1] = h ? r1 : pu[c2 * 4 + 1];
      fr[2] = h ? pu[c2 * 4 + 2] : r0;
      fr[3] = h ? pu[c2 * 4 + 3] : r1;
      pf[c2] = __builtin_bit_cast(half8, fr);
    }

    // ---- PV: O[n=own 32][c=all 256] += P(m-half) V ----
#pragma unroll
    for (int ct = 0; ct < 8; ct++) acc[ct] = MFMA32(pf[0], vf[ct], acc[ct]);
#pragma unroll
    for (int ct = 0; ct < 8; ct++)  // V frags u=1 (reuse regs; RAW-safe)
      vf[ct] = vt8[((size_t)(it * 4 + mh * 2 + 1) * 8 + ct) * 64 + l];
#pragma unroll
    for (int ct = 0; ct < 8; ct++) acc[ct] = MFMA32(pf[1], vf[ct], acc[ct]);

    __syncthreads();  // drains DMA (K(i+1) ready) + releases cur for overwrite
  }

  // ---- epilogue: l over h; acc over mh via LDS; normalize; store ----
  {
    float v = l_part + __shfl_xor(l_part, 32, 64);
    if (l < 32) lsw[mh][nh * 32 + l] = v;
  }
  float* red = (float*)kbuf;  // 64KB = 16384 floats
  if (mh == 1) {
#pragma unroll
    for (int ct = 0; ct < 8; ct++)
#pragma unroll
      for (int k2 = 0; k2 < 4; k2++) {
        f32x4 v4;
#pragma unroll
        for (int r = 0; r < 4; r++) v4[r] = acc[ct][4 * k2 + r];
        *(f32x4*)&red[nh * 8192 + ((ct * 4 + k2) * 64 + l) * 4] = v4;
      }
  }
  __syncthreads();
  if (mh == 0) {
#pragma unroll
    for (int k2 = 0; k2 < 4; k2++) {
      int nb = nh * 32 + 4 * h + 8 * k2;
      f32x4 s0 = *(const f32x4*)&lsw[0][nb];
      f32x4 s1 = *(const f32x4*)&lsw[1][nb];
      f32x4 linv;
#pragma unroll
      for (int r = 0; r < 4; r++) linv[r] = 1.0f / (s0[r] + s1[r]);
#pragma unroll
      for (int ct = 0; ct < 8; ct++) {
        int c = ct * 32 + l31;
        f32x4 ov = *(const f32x4*)&red[nh * 8192 + ((ct * 4 + k2) * 64 + l) * 4];
        f32x4 o4;
#pragma unroll
        for (int r = 0; r < 4; r++) o4[r] = (acc[ct][4 * k2 + r] + ov[r]) * linv[r];
        *(f32x4*)(out + ((size_t)(b * 256 + c)) * 4096 + n0 + nb) = o4;
      }
    }
  }
}

// ---------------------------------------------------------------------------
extern "C" void kernel_launch(void* const* d_in, const int* in_sizes, int n_in,
                              void* d_out, int out_size, void* d_ws,
                              size_t ws_size, hipStream_t stream) {
  const float* x = (const float*)d_in[0];
  const float* condA = (const float*)d_in[1];
  const float* gxw = (const float*)d_in[2];
  const float* gxb = (const float*)d_in[3];
  const float* gcw = (const float*)d_in[4];
  const float* gcb = (const float*)d_in[5];
  const float* qw = (const float*)d_in[6];
  const float* qb = (const float*)d_in[7];
  const float* kw = (const float*)d_in[8];
  const float* kb = (const float*)d_in[9];
  const float* vw = (const float*)d_in[10];
  const float* vb = (const float*)d_in[11];
  float* out = (float*)d_out;

  char* ws = (char*)d_ws;
  float* statsx = (float*)(ws);                     // 2048 B
  float* statsc = (float*)(ws + 2048);              // 2048 B
  _Float16* wqt = (_Float16*)(ws + 4096);           // 128 KB (tiled)
  _Float16* wkt = (_Float16*)(ws + 135168);         // 256 KB (tiled)
  _Float16* wvt = (_Float16*)(ws + 397312);         // 256 KB (tiled)
  char* p = ws + 659456;
  _Float16* hxTt = (_Float16*)p; p += (size_t)8 * 4096 * 256 * 2;  // 16 MB tiled
  _Float16* h1Tt = (_Float16*)p; p += (size_t)8 * 4096 * 512 * 2;  // 32 MB tiled
  _Float16* Qt = (_Float16*)p;   p += (size_t)8 * 4096 * 256 * 2;  // 16 MB tiled
  _Float16* Kt = (_Float16*)p;   p += (size_t)8 * 4096 * 256 * 2;  // 16 MB tiled
  _Float16* Vt = (_Float16*)p;                                     // 16 MB tiled

  statswconv_kernel<<<672, 256, 0, stream>>>(x, condA, statsx, statsc,
                                             qw, kw, vw, wqt, wkt, wvt);
  ntrans_kernel<<<6144, 256, 0, stream>>>(x, condA, statsx, statsc,
                                          gxw, gxb, gcw, gcb, hxTt, h1Tt);
  projQKV_kernel<<<1024, 256, 0, stream>>>(hxTt, h1Tt, wqt, wkt, wvt,
                                           qb, kb, vb, Qt, Kt, Vt);
  attn_kernel<<<512, 256, 0, stream>>>(Qt, Kt, Vt, out);
}